// Round 12
// baseline (178.993 us; speedup 1.0000x reference)
//
#include <hip/hip_runtime.h>

#define N_NODES 50000
#define N_EDGES 800000
#define F1 64
#define F2 16
#define NBINS 196      // ceil(50000/256) node bins
#define BIN_SHIFT 8    // 256 nodes per bin
#define EPB 4096       // edges per binscatter block
#define NSB ((N_EDGES + EPB - 1) / EPB)   // 196 scatter blocks
#define TBW 200        // table row stride (197 used)
#define STAGE_MAX 6144 // max edges per bin (mean 4082, sigma ~64)
#define G1_ROWS 32     // rows per gemm1 block (4 waves x 8 rows)
#define G1_NB ((N_NODES + G1_ROWS - 1) / G1_ROWS)  // 1563
#define GF_NB 6250     // gather1f blocks (2 node-groups each)

typedef _Float16 half_t;
typedef __attribute__((ext_vector_type(8))) _Float16 half8;  // 16 B
typedef __attribute__((ext_vector_type(4))) _Float16 half4;  // 8 B

// ============ launch 1: binscatter (blocks 0..195) || gemm1 (rest) ============
__global__ void __launch_bounds__(256) k_bs_gemm1(
        const int* __restrict__ src, const int* __restrict__ dst,
        unsigned* __restrict__ pairs, int* __restrict__ table,
        const float* __restrict__ x, const float* __restrict__ W1,
        half_t* __restrict__ h0h) {
    __shared__ int smem[5120];   // 20 KB, shared by both branches
    int t = threadIdx.x;         // 256

    if (blockIdx.x < NSB) {
        int* hist    = smem;                     // 196
        int* loff    = smem + 256;               // 197
        int* lcur    = smem + 512;               // 196
        int* scanbuf = smem + 768;               // 256
        unsigned* stage = (unsigned*)(smem + 1024);  // 4096
        int blk = blockIdx.x;
        int e0 = blk * EPB;
        int eend = min(e0 + EPB, N_EDGES);
        int n = eend - e0;

        for (int i = t; i < NBINS; i += 256) hist[i] = 0;
        __syncthreads();
        for (int e = e0 + t; e < eend; e += 256)
            atomicAdd(&hist[dst[e] >> BIN_SHIFT], 1);
        __syncthreads();
        int v = (t < NBINS) ? hist[t] : 0;
        scanbuf[t] = v;
        __syncthreads();
        for (int s = 1; s < 256; s <<= 1) {
            int u = (t >= s) ? scanbuf[t - s] : 0;
            __syncthreads();
            scanbuf[t] += u;
            __syncthreads();
        }
        if (t < NBINS) { loff[t] = scanbuf[t] - v; lcur[t] = scanbuf[t] - v; }
        if (t == 0) loff[NBINS] = n;
        __syncthreads();
        for (int e = e0 + t; e < eend; e += 256) {
            int d = dst[e];
            int b = d >> BIN_SHIFT;
            int pos = atomicAdd(&lcur[b], 1);
            stage[pos] = (unsigned)src[e] | ((unsigned)(d & 255) << 16);  // src < 2^16
        }
        if (t <= NBINS) table[blk * TBW + t] = loff[t];
        __syncthreads();
        for (int i = t; i < n; i += 256) pairs[e0 + i] = stage[i];  // coalesced flush
    } else {
        // gemm1: h0 = fp16(x @ W1), 8 rows/wave in VGPRs, readlane broadcast
        float* Ws = (float*)smem;        // 4096 words
        int bid = blockIdx.x - NSB;
        int lane = t & 63, wid = t >> 6;
        for (int i = t; i < F1 * F1; i += 256) Ws[i] = W1[i];
        int row0 = bid * G1_ROWS + wid * 8;
        float xv[8], acc[8];
#pragma unroll
        for (int r = 0; r < 8; ++r) {
            int row = row0 + r;
            xv[r] = (row < N_NODES) ? x[row * F1 + lane] : 0.f;
            acc[r] = 0.f;
        }
        __syncthreads();
#pragma unroll
        for (int k = 0; k < F1; ++k) {
            float w = Ws[k * F1 + lane];   // 1 LDS read per k, reused x8
#pragma unroll
            for (int r = 0; r < 8; ++r) {
                float xs = __int_as_float(
                    __builtin_amdgcn_readlane(__float_as_int(xv[r]), k));
                acc[r] = fmaf(xs, w, acc[r]);
            }
        }
#pragma unroll
        for (int r = 0; r < 8; ++r) {
            int row = row0 + r;
            if (row < N_NODES) h0h[row * F1 + lane] = (half_t)acc[r];
        }
    }
}

// ============ launch 2: binsort + dinv + PRE-SCALE h0 rows of this bin ============
// bin_start[b] = sum_k table[k][b] (each entry is block-k's exclusive prefix).
// Tail: h0'[row] = dinv[row]*h0[row] for the bin's 256 contiguous rows ->
// gather1f needs NO per-edge dinv load.
__global__ void __launch_bounds__(256) k_binsort(
        const int* __restrict__ table, const unsigned* __restrict__ pairs,
        float* __restrict__ dinv, int* __restrict__ node_start,
        unsigned short* __restrict__ csr, half8* __restrict__ h08) {
    __shared__ int segoff[NSB];
    __shared__ int segcnt[NSB];
    __shared__ int segdst[NSB];
    __shared__ int scanbuf[256];
    __shared__ int hist[256];
    __shared__ int lcur[256];
    __shared__ float dinvs[256];
    __shared__ unsigned stage[STAGE_MAX];         // 24 KB
    __shared__ unsigned short sorted[STAGE_MAX];  // 12 KB
    int t = threadIdx.x, b = blockIdx.x;
    int lane = t & 63, wid = t >> 6;

    // segment descriptors + dual scan: counts -> stage dests, col-sum -> bin_start
    int c = 0, colsum = 0;
    if (t < NSB) {
        int o = table[t * TBW + b];
        segoff[t] = o;
        colsum = o;
        c = table[t * TBW + b + 1] - o;
        segcnt[t] = c;
    }
    scanbuf[t] = c;
    hist[t] = colsum;                  // reuse hist for the column-sum
    __syncthreads();
    for (int s = 1; s < 256; s <<= 1) {
        int u  = (t >= s) ? scanbuf[t - s] : 0;
        int u2 = (t >= s) ? hist[t - s] : 0;
        __syncthreads();
        scanbuf[t] += u;
        hist[t] += u2;
        __syncthreads();
    }
    if (t < NSB) segdst[t] = scanbuf[t] - c;
    int n = scanbuf[255];              // this bin's edge count
    int bstart = hist[255];            // global exclusive start of this bin
    __syncthreads();
    hist[t] = 0;
    __syncthreads();

    // gather the 196 segments into LDS (contiguous)
    for (int k = wid; k < NSB; k += 4) {
        int sc = segcnt[k], base = k * EPB + segoff[k], sd = segdst[k];
        for (int i = lane; i < sc; i += 64) stage[sd + i] = pairs[base + i];
    }
    __syncthreads();

    // node histogram == degree
    for (int i = t; i < n; i += 256) atomicAdd(&hist[stage[i] >> 16], 1);
    __syncthreads();

    int lo = b << BIN_SHIFT;
    int nb = min(256, N_NODES - lo);
    int hv = hist[t];
    float dv = rsqrtf(1.0f + (float)hv);   // +1 self-loop
    dinvs[t] = dv;
    if (t < nb) dinv[lo + t] = dv;
    scanbuf[t] = hv;
    __syncthreads();
    for (int s = 1; s < 256; s <<= 1) {
        int u = (t >= s) ? scanbuf[t - s] : 0;
        __syncthreads();
        scanbuf[t] += u;
        __syncthreads();
    }
    int pr = scanbuf[t] - hv;          // exclusive node prefix within bin
    if (t < nb) node_start[lo + t] = bstart + pr;
    if (b == NBINS - 1 && t == 0) node_start[N_NODES] = N_EDGES;
    lcur[t] = pr;
    __syncthreads();

    // pre-scale this bin's h0 slab (contiguous, coalesced 16B/lane)
    for (int i = t; i < nb * 8; i += 256) {
        half8 v = h08[lo * 8 + i];
        float w = dinvs[i >> 3];
#pragma unroll
        for (int q = 0; q < 8; ++q) v[q] = (half_t)(w * (float)v[q]);
        h08[lo * 8 + i] = v;
    }

    // counting-sort scatter in LDS, coalesced flush
    for (int i = t; i < n; i += 256) {
        unsigned p = stage[i];
        int pos = atomicAdd(&lcur[p >> 16], 1);
        sorted[pos] = (unsigned short)(p & 0xFFFF);
    }
    __syncthreads();
    for (int i = t; i < n; i += 256) csr[bstart + i] = sorted[i];
}

// ============ launch 3: layer-1 gather (pre-scaled fp16 rows) + fused layer-2 GEMM ====
// h0' rows pre-scaled by dinv[src].  h1'[d] = fp16( dinv[d] * relu(dd*(sum+self)+b1) @ W2 )
__global__ void __launch_bounds__(256) k_gather1f(
        const int* __restrict__ node_start, const unsigned short* __restrict__ csr,
        const float* __restrict__ dinv, const half8* __restrict__ h08,
        const float* __restrict__ b1, const float* __restrict__ W2,
        half_t* __restrict__ h1h) {
    __shared__ float W2s[F1 * 17];     // stride 17 breaks bank conflicts
    __shared__ float b1s[F1];
    __shared__ float rowbuf[4][F1];
    int t = threadIdx.x;               // 256 = 4 waves, one node per wave per grp
    for (int i = t; i < F1 * F2; i += 256) W2s[(i >> 4) * 17 + (i & 15)] = W2[i];
    if (t < F1) b1s[t] = b1[t];
    __syncthreads();

    int lane = t & 63, wid = t >> 6;
    int j = lane >> 3, f = lane & 7;   // 8 edge-groups x 16B slice (128 B row)
    int g = lane >> 4, c = lane & 15;  // matmul roles

    for (int grp = blockIdx.x; grp < N_NODES / 4; grp += GF_NB) {  // 2 iterations
        int d = grp * 4 + wid;
        int start = node_start[d], end = node_start[d + 1];
        float acc[8] = {0.f, 0.f, 0.f, 0.f, 0.f, 0.f, 0.f, 0.f};
        int i = start + j;
        for (; i + 8 < end; i += 16) {     // 2 chains, 8 edges/wave/iter
            int s0 = csr[i], s1 = csr[i + 8];
            half8 v0 = h08[s0 * 8 + f], v1 = h08[s1 * 8 + f];   // no dinv load!
#pragma unroll
            for (int q = 0; q < 8; ++q)
                acc[q] += (float)v0[q] + (float)v1[q];
        }
        if (i < end) {
            int s = csr[i];
            half8 v = h08[s * 8 + f];
#pragma unroll
            for (int q = 0; q < 8; ++q) acc[q] += (float)v[q];
        }
#pragma unroll
        for (int m = 8; m <= 32; m <<= 1)
#pragma unroll
            for (int q = 0; q < 8; ++q) acc[q] += __shfl_xor(acc[q], m);

        if (j == 0) {                      // lanes f=0..7 hold the full 64-dim row
            float dd = dinv[d];
            half8 sv = h08[d * 8 + f];     // pre-scaled self row
#pragma unroll
            for (int q = 0; q < 8; ++q) {
                float r = dd * (acc[q] + (float)sv[q]) + b1s[f * 8 + q];
                rowbuf[wid][f * 8 + q] = fmaxf(r, 0.f);
            }
        }
        __syncthreads();

        // 64 -> 16 matmul: g = k-group (16 each), c = output col
        const float* row = rowbuf[wid];
        float p = 0.f;
#pragma unroll
        for (int kk = 0; kk < 16; ++kk)
            p += row[g * 16 + kk] * W2s[(g * 16 + kk) * 17 + c];
        p += __shfl_xor(p, 16);
        p += __shfl_xor(p, 32);
        if (g == 0) h1h[d * F2 + c] = (half_t)(dinv[d] * p);  // pre-scaled for gather2
        __syncthreads();                   // rowbuf reused next grp
    }
}

// ============ launch 4: layer-2 gather: out = b2 + dd*(sum h1'[s] + h1'[d]) ============
__global__ void __launch_bounds__(256) k_gather2(
        const int* __restrict__ node_start, const unsigned short* __restrict__ csr,
        const float* __restrict__ dinv, const half4* __restrict__ h14,
        const float4* __restrict__ b24, float4* __restrict__ out4) {
    int t = threadIdx.x;               // 256 = 4 waves, one node per wave
    int lane = t & 63;
    int j = lane >> 2, f = lane & 3;   // 16 edge-groups x 8B slice (32 B row)
    int d = blockIdx.x * 4 + (t >> 6);
    int start = node_start[d], end = node_start[d + 1];
    float acc[4] = {0.f, 0.f, 0.f, 0.f};
    int i = start + j;
    for (; i + 16 < end; i += 32) {    // 2 chains, 16 edges/wave/iter
        int s0 = csr[i], s1 = csr[i + 16];
        half4 v0 = h14[s0 * 4 + f], v1 = h14[s1 * 4 + f];
#pragma unroll
        for (int q = 0; q < 4; ++q) acc[q] += (float)v0[q] + (float)v1[q];
    }
    if (i < end) {
        int s = csr[i];
        half4 v = h14[s * 4 + f];
#pragma unroll
        for (int q = 0; q < 4; ++q) acc[q] += (float)v[q];
    }
#pragma unroll
    for (int m = 4; m <= 32; m <<= 1)
#pragma unroll
        for (int q = 0; q < 4; ++q) acc[q] += __shfl_xor(acc[q], m);

    if (j == 0) {
        float dd = dinv[d];
        half4 sv = h14[d * 4 + f];
        float4 bb = b24[f];
        float4 r;
        r.x = bb.x + dd * (acc[0] + (float)sv[0]);
        r.y = bb.y + dd * (acc[1] + (float)sv[1]);
        r.z = bb.z + dd * (acc[2] + (float)sv[2]);
        r.w = bb.w + dd * (acc[3] + (float)sv[3]);
        out4[d * 4 + f] = r;
    }
}

extern "C" void kernel_launch(void* const* d_in, const int* in_sizes, int n_in,
                              void* d_out, int out_size, void* d_ws, size_t ws_size,
                              hipStream_t stream) {
    const float* x  = (const float*)d_in[0];          // [50000, 64]
    const int*   ei = (const int*)d_in[1];            // [2, 800000]
    const float* W1 = (const float*)d_in[2];          // [64, 64]
    const float* b1 = (const float*)d_in[3];          // [64]
    const float* W2 = (const float*)d_in[4];          // [64, 16]
    const float* b2 = (const float*)d_in[5];          // [16]
    float* out = (float*)d_out;                       // [50000, 16]

    const int* src = ei;
    const int* dst = ei + N_EDGES;

    // ws layout (4B words), no initialization required, ~13.4 MB:
    int*            table      = (int*)d_ws;                    // 196*200 = 39200
    float*          dinv       = (float*)d_ws + 40960;          // 50000
    int*            node_start = (int*)d_ws + 91008;            // 50001
    unsigned short* csr        = (unsigned short*)((int*)d_ws + 141056);  // 800000 u16
    unsigned*       pairs      = (unsigned*)d_ws + 541056;      // 800000 (block-segmented)
    half_t*         h0h        = (half_t*)((int*)d_ws + 1341056);  // 3.2M fp16 (16B-aligned)
    half_t*         h1h        = (half_t*)((int*)d_ws + 2941056);  // 800K fp16 (pre-scaled)

    k_bs_gemm1<<<NSB + G1_NB, 256, 0, stream>>>(src, dst, pairs, table, x, W1, h0h);
    k_binsort <<<NBINS, 256, 0, stream>>>(table, pairs, dinv, node_start, csr, (half8*)h0h);
    k_gather1f<<<GF_NB, 256, 0, stream>>>(node_start, csr, dinv, (const half8*)h0h,
                                          b1, W2, h1h);
    k_gather2 <<<N_NODES / 4, 256, 0, stream>>>(node_start, csr, dinv, (const half4*)h1h,
                                                (const float4*)b2, (float4*)out);
}

// Round 13
// 168.405 us; speedup vs baseline: 1.0629x; 1.0629x over previous
//
#include <hip/hip_runtime.h>

#define N_NODES 50000
#define N_EDGES 800000
#define F1 64
#define F2 16
#define NBINS 196      // ceil(50000/256) node bins
#define BIN_SHIFT 8    // 256 nodes per bin
#define EPB 8192       // edges per binscatter block (bigger segments -> binsort lane util)
#define NSB ((N_EDGES + EPB - 1) / EPB)   // 98 scatter blocks
#define TBW 200        // table row stride (197 used)
#define STAGE_MAX 6144 // max edges per bin (mean 4082, sigma ~64)
#define G1_ROWS 32     // rows per gemm1 block (4 waves x 8 rows)
#define G1_NB ((N_NODES + G1_ROWS - 1) / G1_ROWS)  // 1563

typedef _Float16 half_t;
typedef __attribute__((ext_vector_type(8))) _Float16 half8;  // 16 B
typedef __attribute__((ext_vector_type(4))) _Float16 half4;  // 8 B

// ============ launch 1: binscatter (blocks 0..NSB-1) || gemm1 (rest) ============
// binscatter: bin edges by dst>>8 into BLOCK-SEGMENTED layout (pairs[blk*EPB..])
// + per-block bin-offset table. No inter-block dependency -> fuses with gemm1.
__global__ void __launch_bounds__(256) k_bs_gemm1(
        const int* __restrict__ src, const int* __restrict__ dst,
        unsigned* __restrict__ pairs, int* __restrict__ table,
        const float* __restrict__ x, const float* __restrict__ W1,
        half_t* __restrict__ h0h) {
    __shared__ int smem[1024 + EPB];   // 36 KB, shared by both branches
    int t = threadIdx.x;               // 256

    if (blockIdx.x < NSB) {
        int* hist    = smem;                     // 196
        int* loff    = smem + 256;               // 197
        int* lcur    = smem + 512;               // 196
        int* scanbuf = smem + 768;               // 256
        unsigned* stage = (unsigned*)(smem + 1024);  // EPB
        int blk = blockIdx.x;
        int e0 = blk * EPB;
        int eend = min(e0 + EPB, N_EDGES);
        int n = eend - e0;

        for (int i = t; i < NBINS; i += 256) hist[i] = 0;
        __syncthreads();
        for (int e = e0 + t; e < eend; e += 256)
            atomicAdd(&hist[dst[e] >> BIN_SHIFT], 1);
        __syncthreads();
        int v = (t < NBINS) ? hist[t] : 0;
        scanbuf[t] = v;
        __syncthreads();
        for (int s = 1; s < 256; s <<= 1) {
            int u = (t >= s) ? scanbuf[t - s] : 0;
            __syncthreads();
            scanbuf[t] += u;
            __syncthreads();
        }
        if (t < NBINS) { loff[t] = scanbuf[t] - v; lcur[t] = scanbuf[t] - v; }
        if (t == 0) loff[NBINS] = n;
        __syncthreads();
        for (int e = e0 + t; e < eend; e += 256) {
            int d = dst[e];
            int b = d >> BIN_SHIFT;
            int pos = atomicAdd(&lcur[b], 1);
            stage[pos] = (unsigned)src[e] | ((unsigned)(d & 255) << 16);  // src < 2^16
        }
        if (t <= NBINS) table[blk * TBW + t] = loff[t];
        __syncthreads();
        for (int i = t; i < n; i += 256) pairs[e0 + i] = stage[i];  // coalesced flush
    } else {
        // gemm1: h0 = fp16(x @ W1), 8 rows/wave in registers, readlane broadcast,
        // zero per-FMA LDS traffic.
        float* Ws = (float*)smem;        // 4096 words
        int bid = blockIdx.x - NSB;
        int lane = t & 63, wid = t >> 6;
        for (int i = t; i < F1 * F1; i += 256) Ws[i] = W1[i];
        int row0 = bid * G1_ROWS + wid * 8;
        float xv[8], acc[8];
#pragma unroll
        for (int r = 0; r < 8; ++r) {
            int row = row0 + r;
            xv[r] = (row < N_NODES) ? x[row * F1 + lane] : 0.f;
            acc[r] = 0.f;
        }
        __syncthreads();
#pragma unroll
        for (int k = 0; k < F1; ++k) {
            float w = Ws[k * F1 + lane];   // 1 LDS read per k, reused x8
#pragma unroll
            for (int r = 0; r < 8; ++r) {
                float xs = __int_as_float(
                    __builtin_amdgcn_readlane(__float_as_int(xv[r]), k));
                acc[r] = fmaf(xs, w, acc[r]);
            }
        }
#pragma unroll
        for (int r = 0; r < 8; ++r) {
            int row = row0 + r;
            if (row < N_NODES) h0h[row * F1 + lane] = (half_t)acc[r];
        }
    }
}

// ============ launch 2: binsort (bin_start via table column-sum) ============
// bin_start[b] = sum_k table[k][b] since each entry is block-k's exclusive prefix.
__global__ void __launch_bounds__(256) k_binsort(
        const int* __restrict__ table, const unsigned* __restrict__ pairs,
        float* __restrict__ dinv, int* __restrict__ node_start,
        unsigned short* __restrict__ csr) {
    __shared__ int segoff[NSB];
    __shared__ int segcnt[NSB];
    __shared__ int segdst[NSB];
    __shared__ int scanbuf[256];
    __shared__ int hist[256];
    __shared__ int lcur[256];
    __shared__ unsigned stage[STAGE_MAX];         // 24 KB
    __shared__ unsigned short sorted[STAGE_MAX];  // 12 KB
    int t = threadIdx.x, b = blockIdx.x;
    int lane = t & 63, wid = t >> 6;

    // segment descriptors + dual scan: counts -> stage dests, col-sum -> bin_start
    int c = 0, colsum = 0;
    if (t < NSB) {
        int o = table[t * TBW + b];
        segoff[t] = o;
        colsum = o;
        c = table[t * TBW + b + 1] - o;
        segcnt[t] = c;
    }
    scanbuf[t] = c;
    hist[t] = colsum;                  // reuse hist for the column-sum
    __syncthreads();
    for (int s = 1; s < 256; s <<= 1) {
        int u  = (t >= s) ? scanbuf[t - s] : 0;
        int u2 = (t >= s) ? hist[t - s] : 0;
        __syncthreads();
        scanbuf[t] += u;
        hist[t] += u2;
        __syncthreads();
    }
    if (t < NSB) segdst[t] = scanbuf[t] - c;
    int n = scanbuf[255];              // this bin's edge count
    int bstart = hist[255];            // global exclusive start of this bin
    __syncthreads();
    hist[t] = 0;
    __syncthreads();

    // gather the NSB segments into LDS (contiguous); ~84-edge avg per segment
    for (int k = wid; k < NSB; k += 4) {
        int sc = segcnt[k], base = k * EPB + segoff[k], sd = segdst[k];
        for (int i = lane; i < sc; i += 64) stage[sd + i] = pairs[base + i];
    }
    __syncthreads();

    // node histogram == degree
    for (int i = t; i < n; i += 256) atomicAdd(&hist[stage[i] >> 16], 1);
    __syncthreads();

    int lo = b << BIN_SHIFT;
    int nb = min(256, N_NODES - lo);
    int hv = hist[t];
    if (t < nb) dinv[lo + t] = rsqrtf(1.0f + (float)hv);  // +1 self-loop
    scanbuf[t] = hv;
    __syncthreads();
    for (int s = 1; s < 256; s <<= 1) {
        int u = (t >= s) ? scanbuf[t - s] : 0;
        __syncthreads();
        scanbuf[t] += u;
        __syncthreads();
    }
    int pr = scanbuf[t] - hv;          // exclusive node prefix within bin
    if (t < nb) node_start[lo + t] = bstart + pr;
    if (b == NBINS - 1 && t == 0) node_start[N_NODES] = N_EDGES;
    lcur[t] = pr;
    __syncthreads();

    // counting-sort scatter in LDS, coalesced flush
    for (int i = t; i < n; i += 256) {
        unsigned p = stage[i];
        int pos = atomicAdd(&lcur[p >> 16], 1);
        sorted[pos] = (unsigned short)(p & 0xFFFF);
    }
    __syncthreads();
    for (int i = t; i < n; i += 256) csr[bstart + i] = sorted[i];
}

// ============ launch 3: layer-1 gather (fp16 rows) + fused layer-2 GEMM ============
// agg[d] = dd*( sum_s dinv[s]*h0[s] + dd*h0[d] );  h1'[d] = fp16( dd * relu(agg+b1)@W2 )
__global__ void __launch_bounds__(256) k_gather1f(
        const int* __restrict__ node_start, const unsigned short* __restrict__ csr,
        const float* __restrict__ dinv, const half8* __restrict__ h08,
        const float* __restrict__ b1, const float* __restrict__ W2,
        half_t* __restrict__ h1h) {
    __shared__ float W2s[F1 * 17];     // stride 17 breaks bank conflicts
    __shared__ float b1s[F1];
    __shared__ float rowbuf[4][F1];
    int t = threadIdx.x;               // 256 = 4 waves, one node per wave
    for (int i = t; i < F1 * F2; i += 256) W2s[(i >> 4) * 17 + (i & 15)] = W2[i];
    if (t < F1) b1s[t] = b1[t];
    __syncthreads();

    int lane = t & 63, wid = t >> 6;
    int j = lane >> 3, f = lane & 7;   // 8 edge-groups x 16B slice (128 B row)
    int d = blockIdx.x * 4 + wid;
    int start = node_start[d], end = node_start[d + 1];
    float acc[8] = {0.f, 0.f, 0.f, 0.f, 0.f, 0.f, 0.f, 0.f};
    int i = start + j;
    for (; i + 8 < end; i += 16) {     // 2 chains, 8 edges/wave/iter
        int s0 = csr[i], s1 = csr[i + 8];
        float w0 = dinv[s0], w1 = dinv[s1];
        half8 v0 = h08[s0 * 8 + f], v1 = h08[s1 * 8 + f];
#pragma unroll
        for (int q = 0; q < 8; ++q)
            acc[q] += w0 * (float)v0[q] + w1 * (float)v1[q];
    }
    if (i < end) {
        int s = csr[i];
        float w = dinv[s];
        half8 v = h08[s * 8 + f];
#pragma unroll
        for (int q = 0; q < 8; ++q) acc[q] += w * (float)v[q];
    }
#pragma unroll
    for (int m = 8; m <= 32; m <<= 1)
#pragma unroll
        for (int q = 0; q < 8; ++q) acc[q] += __shfl_xor(acc[q], m);

    if (j == 0) {                      // lanes f=0..7 hold the full 64-dim row
        float dd = dinv[d];
        half8 sv = h08[d * 8 + f];
#pragma unroll
        for (int q = 0; q < 8; ++q) {
            float r = dd * (acc[q] + dd * (float)sv[q]) + b1s[f * 8 + q];
            rowbuf[wid][f * 8 + q] = fmaxf(r, 0.f);
        }
    }
    __syncthreads();

    // 64 -> 16 matmul: g = k-group (16 each), c = output col
    int g = lane >> 4, c = lane & 15;
    const float* row = rowbuf[wid];
    float p = 0.f;
#pragma unroll
    for (int kk = 0; kk < 16; ++kk)
        p += row[g * 16 + kk] * W2s[(g * 16 + kk) * 17 + c];
    p += __shfl_xor(p, 16);
    p += __shfl_xor(p, 32);
    if (g == 0) h1h[d * F2 + c] = (half_t)(dinv[d] * p);   // pre-scaled for gather2
}

// ============ launch 4: layer-2 gather: out = b2 + dd*(sum h1'[s] + h1'[d]) ============
__global__ void __launch_bounds__(256) k_gather2(
        const int* __restrict__ node_start, const unsigned short* __restrict__ csr,
        const float* __restrict__ dinv, const half4* __restrict__ h14,
        const float4* __restrict__ b24, float4* __restrict__ out4) {
    int t = threadIdx.x;               // 256 = 4 waves, one node per wave
    int lane = t & 63;
    int j = lane >> 2, f = lane & 3;   // 16 edge-groups x 8B slice (32 B row)
    int d = blockIdx.x * 4 + (t >> 6);
    int start = node_start[d], end = node_start[d + 1];
    float acc[4] = {0.f, 0.f, 0.f, 0.f};
    int i = start + j;
    for (; i + 16 < end; i += 32) {    // 2 chains, 16 edges/wave/iter
        int s0 = csr[i], s1 = csr[i + 16];
        half4 v0 = h14[s0 * 4 + f], v1 = h14[s1 * 4 + f];
#pragma unroll
        for (int q = 0; q < 4; ++q) acc[q] += (float)v0[q] + (float)v1[q];
    }
    if (i < end) {
        int s = csr[i];
        half4 v = h14[s * 4 + f];
#pragma unroll
        for (int q = 0; q < 4; ++q) acc[q] += (float)v[q];
    }
#pragma unroll
    for (int m = 4; m <= 32; m <<= 1)
#pragma unroll
        for (int q = 0; q < 4; ++q) acc[q] += __shfl_xor(acc[q], m);

    if (j == 0) {
        float dd = dinv[d];
        half4 sv = h14[d * 4 + f];
        float4 bb = b24[f];
        float4 r;
        r.x = bb.x + dd * (acc[0] + (float)sv[0]);
        r.y = bb.y + dd * (acc[1] + (float)sv[1]);
        r.z = bb.z + dd * (acc[2] + (float)sv[2]);
        r.w = bb.w + dd * (acc[3] + (float)sv[3]);
        out4[d * 4 + f] = r;
    }
}

extern "C" void kernel_launch(void* const* d_in, const int* in_sizes, int n_in,
                              void* d_out, int out_size, void* d_ws, size_t ws_size,
                              hipStream_t stream) {
    const float* x  = (const float*)d_in[0];          // [50000, 64]
    const int*   ei = (const int*)d_in[1];            // [2, 800000]
    const float* W1 = (const float*)d_in[2];          // [64, 64]
    const float* b1 = (const float*)d_in[3];          // [64]
    const float* W2 = (const float*)d_in[4];          // [64, 16]
    const float* b2 = (const float*)d_in[5];          // [16]
    float* out = (float*)d_out;                       // [50000, 16]

    const int* src = ei;
    const int* dst = ei + N_EDGES;

    // ws layout (4B words), no initialization required, ~13.4 MB:
    int*            table      = (int*)d_ws;                    // 98*200
    float*          dinv       = (float*)d_ws + 40960;          // 50000
    int*            node_start = (int*)d_ws + 91008;            // 50001
    unsigned short* csr        = (unsigned short*)((int*)d_ws + 141056);  // 800000 u16
    unsigned*       pairs      = (unsigned*)d_ws + 541056;      // 800000+ (block-segmented)
    half_t*         h0h        = (half_t*)((int*)d_ws + 1345056);  // 3.2M fp16 (16B-aligned)
    half_t*         h1h        = (half_t*)((int*)d_ws + 2945056);  // 800K fp16 (pre-scaled)

    k_bs_gemm1<<<NSB + G1_NB, 256, 0, stream>>>(src, dst, pairs, table, x, W1, h0h);
    k_binsort <<<NBINS, 256, 0, stream>>>(table, pairs, dinv, node_start, csr);
    k_gather1f<<<N_NODES / 4, 256, 0, stream>>>(node_start, csr, dinv, (const half8*)h0h,
                                                b1, W2, h1h);
    k_gather2 <<<N_NODES / 4, 256, 0, stream>>>(node_start, csr, dinv, (const half4*)h1h,
                                                (const float4*)b2, (float4*)out);
}